// Round 3
// baseline (1048.195 us; speedup 1.0000x reference)
//
#include <hip/hip_runtime.h>
#include <math.h>

// Problem constants
#define DIM   384
#define NQKV  1152
#define IMG   56
#define NH    12
#define EDIM  32
#define ROWS_PER_B (IMG*IMG)           // 3136 pixels per batch image
#define QB_PER_B   (ROWS_PER_B*DIM)    // 1,204,224 floats per batch per buffer

// ---------------------------------------------------------------------------
// Kernel 1: relative sinusoidal embedding table (49x49), bit-faithful to numpy.
// numpy arange (PyArray_Arange + _fill): x[0]=1; x[1]=fl(1+fl(1/7));
// delta=fl(x[1]-x[0]); x[i]=fl(1 + fl(i*delta)).  NOTE delta != fl(1/7):
// delta = fl(1/7) - 2^-54, so e.g. x[7]-x[0] = 0.99999999999999956 -> xi=0,
// NOT 1. The trunc toward zero (.astype(int32)) is discontinuous there, so
// the exact rounding sequence must be replicated (_rn intrinsics block FMA).
// The uniform formula reproduces x[0] and x[1] bit-exactly too.
// ---------------------------------------------------------------------------
__global__ __launch_bounds__(256) void emb_init_kernel(float* __restrict__ emb) {
    int idx = blockIdx.x * 256 + threadIdx.x;
    if (idx >= 49 * 49) return;
    int q = idx / 49, k = idx % 49;

    const double step  = 1.0 / 7.0;                           // fl(1/7)
    const double delta = __dsub_rn(__dadd_rn(1.0, step), 1.0); // numpy fill delta
    double xk = __dadd_rn(1.0, __dmul_rn((double)k, delta));
    double xq = __dadd_rn(1.0, __dmul_rn((double)q, delta));
    int xi = (int)__dsub_rn(xk, xq);                          // trunc toward zero
    int yi = (k % 7) - (q % 7);

    int r = xi % 13; if (r < 0) r += 13;                      // python negative index wrap
    int c = yi % 13; if (c < 0) c += 13;

    const float scl = (float)(-0.7084877209212449);           // -log(10000)/13
    float val;
    if ((c & 1) == 0) {
        float dv = expf((float)c * scl);                      // 2*(c/2) == c
        val = sinf((float)r * dv);
    } else {
        float dv = expf((float)(c - 1) * scl);                // 2*((c-1)/2) == c-1
        val = cosf((float)r * dv);
    }
    emb[idx] = val;
}

// ---------------------------------------------------------------------------
// Kernel 2/4: fp32 tiled SGEMM, 64x64 tile, BK=16, 256 threads, 4x4/thread.
// MODE 0: QKV projection, epilogue de-interleaves column j -> (comp=j%3, ch=j/3)
//         into out0/out1/out2 (Q/K/V buffers, [rows][384]).
// MODE 1: plain C = A@W + bias into out0 (row stride N).
// ---------------------------------------------------------------------------
template <int MODE>
__global__ __launch_bounds__(256) void sgemm64(
    const float* __restrict__ A, const float* __restrict__ W,
    const float* __restrict__ bias,
    float* __restrict__ out0, float* __restrict__ out1, float* __restrict__ out2,
    int N, int K)
{
    __shared__ float As[16][64];    // [k][m]
    __shared__ float Bs[16][68];    // [k][n], padded row

    const int bn = blockIdx.x, bm = blockIdx.y;
    const int tid = threadIdx.x;
    const int tx = tid & 15, ty = tid >> 4;

    const int arow = tid >> 2;            // 0..63
    const int ac4  = (tid & 3) << 2;      // 0,4,8,12
    const int brow = tid >> 4;            // 0..15
    const int bc4  = (tid & 15) << 2;     // 0..60

    const float* Ap = A + (size_t)(bm * 64 + arow) * K + ac4;
    const float* Wp = W + (size_t)brow * N + bn * 64 + bc4;

    float acc[4][4] = {};

    for (int kt = 0; kt < K; kt += 16) {
        float4 av = *(const float4*)(Ap + kt);
        float4 wv = *(const float4*)(Wp + (size_t)kt * N);
        As[ac4 + 0][arow] = av.x;
        As[ac4 + 1][arow] = av.y;
        As[ac4 + 2][arow] = av.z;
        As[ac4 + 3][arow] = av.w;
        *(float4*)&Bs[brow][bc4] = wv;
        __syncthreads();
        #pragma unroll
        for (int kk = 0; kk < 16; ++kk) {
            float4 a  = *(const float4*)&As[kk][ty * 4];
            float4 bv = *(const float4*)&Bs[kk][tx * 4];
            float ar[4] = {a.x, a.y, a.z, a.w};
            float br[4] = {bv.x, bv.y, bv.z, bv.w};
            #pragma unroll
            for (int i = 0; i < 4; ++i)
                #pragma unroll
                for (int j = 0; j < 4; ++j)
                    acc[i][j] += ar[i] * br[j];
        }
        __syncthreads();
    }

    #pragma unroll
    for (int i = 0; i < 4; ++i) {
        int gr = bm * 64 + ty * 4 + i;
        #pragma unroll
        for (int j = 0; j < 4; ++j) {
            int gc = bn * 64 + tx * 4 + j;
            float v = acc[i][j] + bias[gc];
            if constexpr (MODE == 0) {
                int comp = gc % 3, ch = gc / 3;
                float* dst = (comp == 0) ? out0 : ((comp == 1) ? out1 : out2);
                dst[(size_t)gr * DIM + ch] = v;
            } else {
                out0[(size_t)gr * N + gc] = v;
            }
        }
    }
}

// ---------------------------------------------------------------------------
// Kernel 3: windowed attention. One block per (b_local, head, wh, ww).
// Gathers Q/K/V with roll(-4,-4) fused; writes att with roll(+3,+3) fused.
// ---------------------------------------------------------------------------
__global__ __launch_bounds__(256) void attn_kernel(
    const float* __restrict__ qb, const float* __restrict__ kb,
    const float* __restrict__ vb, const float* __restrict__ emb,
    float* __restrict__ att)
{
    __shared__ float Qs[49][33];
    __shared__ float Ks[49][33];
    __shared__ float Vs[49][33];
    __shared__ float S[49][49];

    const int blk = blockIdx.x;
    const int bw = blk & 7;
    const int bh = (blk >> 3) & 7;
    const int n  = (blk >> 6) % 12;
    const int b  = blk / 768;            // local batch within chunk
    const int tid = threadIdx.x;

    // load Q/K/V tiles (49 pixels x 32 channels), shift roll(-4,-4) fused
    for (int i = tid; i < 49 * 32; i += 256) {
        int pix = i >> 5, e = i & 31;
        int m1 = pix / 7, m2 = pix % 7;
        int gr = (bh * 7 + m1 + 4) % IMG;
        int gc = (bw * 7 + m2 + 4) % IMG;
        size_t base = ((size_t)(b * IMG + gr) * IMG + gc) * DIM + n * EDIM + e;
        Qs[pix][e] = qb[base];
        Ks[pix][e] = kb[base];
        Vs[pix][e] = vb[base];
    }
    __syncthreads();

    const float scale = 0.17677669529663687f;   // 1/sqrt(32)
    const bool rowm = (bh == 7), colm = (bw == 7);
    for (int s = tid; s < 49 * 49; s += 256) {
        int q = s / 49, k = s % 49;
        float acc = 0.f;
        #pragma unroll
        for (int e = 0; e < 32; ++e) acc += Qs[q][e] * Ks[k][e];
        float v = acc * scale + emb[s];
        if (rowm && ((q >= 28) != (k >= 28))) v = -INFINITY;
        if (colm && ((q % 7 >= 4) != (k % 7 >= 4))) v = -INFINITY;
        S[q][k] = v;
    }
    __syncthreads();

    // softmax per row
    if (tid < 49) {
        float m = -INFINITY;
        for (int k = 0; k < 49; ++k) m = fmaxf(m, S[tid][k]);
        float sum = 0.f;
        for (int k = 0; k < 49; ++k) {
            float p = expf(S[tid][k] - m);
            S[tid][k] = p;
            sum += p;
        }
        float inv = 1.f / sum;
        for (int k = 0; k < 49; ++k) S[tid][k] *= inv;
    }
    __syncthreads();

    // P @ V, write back with un-shift roll(+3,+3) fused
    for (int i = tid; i < 49 * 32; i += 256) {
        int q = i >> 5, e = i & 31;
        float acc = 0.f;
        for (int k = 0; k < 49; ++k) acc += S[q][k] * Vs[k][e];
        int rp = bh * 7 + q / 7, cp = bw * 7 + q % 7;
        int fr = (rp + 3) % IMG, fc = (cp + 3) % IMG;
        att[((size_t)(b * IMG + fr) * IMG + fc) * DIM + n * EDIM + e] = acc;
    }
}

// ---------------------------------------------------------------------------
extern "C" void kernel_launch(void* const* d_in, const int* in_sizes, int n_in,
                              void* d_out, int out_size, void* d_ws, size_t ws_size,
                              hipStream_t stream) {
    const float* x     = (const float*)d_in[0];
    const float* w_qkv = (const float*)d_in[1];
    const float* b_qkv = (const float*)d_in[2];
    const float* w_out = (const float*)d_in[3];
    const float* b_out = (const float*)d_in[4];
    float* out = (float*)d_out;

    // Adaptive batch chunking: per batch we need Q,K,V,att = 4 * 1,204,224 floats.
    // Pick the largest nb in {8,4,2,1} that fits ws_size (deterministic per run).
    const size_t Ffloats = ws_size / 4;
    const size_t perb = 4ull * QB_PER_B;
    int nb = 8;
    while (nb > 1 && 4096ull + (size_t)nb * perb > Ffloats) nb >>= 1;

    float* emb = (float*)d_ws;               // 2401 floats (4096 slot)
    float* qb  = emb + 4096;
    float* kb  = qb + (size_t)nb * QB_PER_B;
    float* vb  = kb + (size_t)nb * QB_PER_B;
    float* att = vb + (size_t)nb * QB_PER_B;

    emb_init_kernel<<<(49 * 49 + 255) / 256, 256, 0, stream>>>(emb);

    for (int b0 = 0; b0 < 16; b0 += nb) {
        const float* xa = x + (size_t)b0 * QB_PER_B;      // rows b0*3136 .., K=384
        // QKV projection for nb batches: M = nb*3136, N = 1152, K = 384
        sgemm64<0><<<dim3(NQKV / 64, nb * (ROWS_PER_B / 64)), 256, 0, stream>>>(
            xa, w_qkv, b_qkv, qb, kb, vb, NQKV, DIM);
        // windowed attention for nb batches
        attn_kernel<<<nb * 12 * 8 * 8, 256, 0, stream>>>(qb, kb, vb, emb, att);
        // out projection: M = nb*3136, N = 384, K = 384
        sgemm64<1><<<dim3(DIM / 64, nb * (ROWS_PER_B / 64)), 256, 0, stream>>>(
            att, w_out, b_out, out + (size_t)b0 * QB_PER_B, nullptr, nullptr, DIM, DIM);
    }
}

// Round 4
// 381.205 us; speedup vs baseline: 2.7497x; 2.7497x over previous
//
#include <hip/hip_runtime.h>
#include <math.h>

// Problem constants
#define DIM   384
#define NQKV  1152
#define IMG   56
#define ROWS_PER_B (IMG*IMG)           // 3136 pixels per batch image

typedef unsigned short u16;
typedef __attribute__((ext_vector_type(4))) float f32x4;
typedef __attribute__((ext_vector_type(8))) short s16x8;

__device__ __forceinline__ u16 f2b(float f) {           // fp32 -> bf16 RNE
    unsigned u = __float_as_uint(f);
    return (u16)((u + 0x7fffu + ((u >> 16) & 1u)) >> 16);
}
__device__ __forceinline__ float b2f(u16 h) {
    return __uint_as_float(((unsigned)h) << 16);
}

// ---------------------------------------------------------------------------
// Kernel 1: relative sinusoidal embedding table (49x49), bit-faithful to numpy
// arange fill: delta = fl(fl(1+1/7)-1);  x[i] = fl(1 + fl(i*delta)).
// delta != fl(1/7) (off by 2^-54) and the .astype(int32) trunc is
// discontinuous at multiples of 7, so the exact rounding sequence matters.
// DO NOT TOUCH — verified passing in Round 3.
// ---------------------------------------------------------------------------
__global__ __launch_bounds__(256) void emb_init_kernel(float* __restrict__ emb) {
    int idx = blockIdx.x * 256 + threadIdx.x;
    if (idx >= 49 * 49) return;
    int q = idx / 49, k = idx % 49;

    const double step  = 1.0 / 7.0;
    const double delta = __dsub_rn(__dadd_rn(1.0, step), 1.0);
    double xk = __dadd_rn(1.0, __dmul_rn((double)k, delta));
    double xq = __dadd_rn(1.0, __dmul_rn((double)q, delta));
    int xi = (int)__dsub_rn(xk, xq);
    int yi = (k % 7) - (q % 7);

    int r = xi % 13; if (r < 0) r += 13;
    int c = yi % 13; if (c < 0) c += 13;

    const float scl = (float)(-0.7084877209212449);      // -log(10000)/13
    float val;
    if ((c & 1) == 0) val = sinf((float)r * expf((float)c * scl));
    else              val = cosf((float)r * expf((float)(c - 1) * scl));
    emb[idx] = val;
}

// ---------------------------------------------------------------------------
// Conversion kernels
// ---------------------------------------------------------------------------
__global__ __launch_bounds__(256) void cvt_f32_bf16(
    const float* __restrict__ in, u16* __restrict__ out, int n4) {
    int i = blockIdx.x * 256 + threadIdx.x;
    if (i >= n4) return;
    float4 v = ((const float4*)in)[i];
    ushort4 o;
    o.x = f2b(v.x); o.y = f2b(v.y); o.z = f2b(v.z); o.w = f2b(v.w);
    ((ushort4*)out)[i] = o;
}

// w [R][C] fp32  ->  wt [C][R] bf16   (tiny, launched once)
__global__ __launch_bounds__(256) void cvt_transpose_bf16(
    const float* __restrict__ w, u16* __restrict__ wt, int R, int C) {
    int i = blockIdx.x * 256 + threadIdx.x;
    if (i >= R * C) return;
    int r = i / C, c = i % C;
    wt[(size_t)c * R + r] = f2b(w[i]);
}

// ---------------------------------------------------------------------------
// MFMA bf16 GEMM: C[M][N] = A[M][K] @ Bt[N][K]^T + bias.
// 128x128 tile, BK=32, 256 threads = 4 waves, each wave a 64x64 sub-tile
// (4x4 fragments of 16x16x32). LDS [128][40] bf16 (pad -> 2-way conflicts,
// free per m136). C/D layout: col = lane&15, row = (lane>>4)*4 + reg (m89).
// MODE 0: bf16 output (QKV, N=1152 interleaved (ch,comp) natural order).
// MODE 1: fp32 output + bias (final projection).
// Requires M%128==0, N%128==0, K%32==0.
// ---------------------------------------------------------------------------
template <int MODE>
__global__ __launch_bounds__(256) void mfma_gemm(
    const u16* __restrict__ A, const u16* __restrict__ Bt,
    const float* __restrict__ bias,
    u16* __restrict__ outb, float* __restrict__ outf,
    int N, int K)
{
    __shared__ __align__(16) u16 As[128][40];
    __shared__ __align__(16) u16 Bs[128][40];

    const int tid  = threadIdx.x;
    const int lane = tid & 63;
    const int wid  = tid >> 6;
    const int wr   = wid >> 1, wc = wid & 1;     // wave -> 64x64 quadrant
    const int l15  = lane & 15, l4 = lane >> 4;
    const int bm = blockIdx.y, bn = blockIdx.x;

    // staging: thread t covers rows (t>>2) and (t>>2)+64, k-span (t&3)*8..+7
    const int srow = tid >> 2;
    const int sk   = (tid & 3) * 8;

    const u16* Ap = A  + (size_t)(bm * 128 + srow) * K + sk;
    const u16* Bp = Bt + (size_t)(bn * 128 + srow) * K + sk;

    f32x4 acc[4][4] = {};

    for (int kt = 0; kt < K; kt += 32) {
        s16x8 a0 = *(const s16x8*)(Ap + kt);
        s16x8 a1 = *(const s16x8*)(Ap + (size_t)64 * K + kt);
        s16x8 b0 = *(const s16x8*)(Bp + kt);
        s16x8 b1 = *(const s16x8*)(Bp + (size_t)64 * K + kt);
        __syncthreads();                       // prev-iter LDS reads done
        *(s16x8*)&As[srow][sk]      = a0;
        *(s16x8*)&As[srow + 64][sk] = a1;
        *(s16x8*)&Bs[srow][sk]      = b0;
        *(s16x8*)&Bs[srow + 64][sk] = b1;
        __syncthreads();

        s16x8 af[4], bf[4];
        #pragma unroll
        for (int m = 0; m < 4; ++m)
            af[m] = *(const s16x8*)&As[wr * 64 + m * 16 + l15][l4 * 8];
        #pragma unroll
        for (int n = 0; n < 4; ++n)
            bf[n] = *(const s16x8*)&Bs[wc * 64 + n * 16 + l15][l4 * 8];
        #pragma unroll
        for (int m = 0; m < 4; ++m)
            #pragma unroll
            for (int n = 0; n < 4; ++n)
                acc[m][n] = __builtin_amdgcn_mfma_f32_16x16x32_bf16(
                    af[m], bf[n], acc[m][n], 0, 0, 0);
    }

    const int grow0 = bm * 128 + wr * 64;
    const int gcol0 = bn * 128 + wc * 64;
    #pragma unroll
    for (int m = 0; m < 4; ++m) {
        #pragma unroll
        for (int n = 0; n < 4; ++n) {
            int col = gcol0 + n * 16 + l15;
            float bz = bias[col];
            #pragma unroll
            for (int r = 0; r < 4; ++r) {
                int row = grow0 + m * 16 + l4 * 4 + r;
                float v = acc[m][n][r] + bz;
                if constexpr (MODE == 0)
                    outb[(size_t)row * N + col] = f2b(v);
                else
                    outf[(size_t)row * N + col] = v;
            }
        }
    }
}

// ---------------------------------------------------------------------------
// Kernel 3: windowed attention. One block per (b_local, head, wh, ww).
// qkv is bf16 [rows][1152] with column gc = ch*3 + comp (GEMM-natural order).
// Gathers with roll(-4,-4) fused; writes att bf16 [rows][384] with roll(+3,+3).
// ---------------------------------------------------------------------------
__global__ __launch_bounds__(256) void attn_kernel(
    const u16* __restrict__ qkv, const float* __restrict__ emb,
    u16* __restrict__ att)
{
    __shared__ float Qs[49][33];
    __shared__ float Ks[49][33];
    __shared__ float Vs[49][33];
    __shared__ float S[49][49];

    const int blk = blockIdx.x;
    const int bw = blk & 7;
    const int bh = (blk >> 3) & 7;
    const int n  = (blk >> 6) % 12;
    const int b  = blk / 768;            // local batch within chunk
    const int tid = threadIdx.x;

    for (int i = tid; i < 49 * 32; i += 256) {
        int pix = i >> 5, e = i & 31;
        int m1 = pix / 7, m2 = pix % 7;
        int gr = (bh * 7 + m1 + 4) % IMG;
        int gc = (bw * 7 + m2 + 4) % IMG;
        size_t base = ((size_t)(b * IMG + gr) * IMG + gc) * NQKV + (size_t)(n * 32 + e) * 3;
        Qs[pix][e] = b2f(qkv[base + 0]);
        Ks[pix][e] = b2f(qkv[base + 1]);
        Vs[pix][e] = b2f(qkv[base + 2]);
    }
    __syncthreads();

    const float scale = 0.17677669529663687f;   // 1/sqrt(32)
    const bool rowm = (bh == 7), colm = (bw == 7);
    for (int s = tid; s < 49 * 49; s += 256) {
        int q = s / 49, k = s % 49;
        float acc = 0.f;
        #pragma unroll
        for (int e = 0; e < 32; ++e) acc += Qs[q][e] * Ks[k][e];
        float v = acc * scale + emb[s];
        if (rowm && ((q >= 28) != (k >= 28))) v = -INFINITY;
        if (colm && ((q % 7 >= 4) != (k % 7 >= 4))) v = -INFINITY;
        S[q][k] = v;
    }
    __syncthreads();

    if (tid < 49) {
        float m = -INFINITY;
        for (int k = 0; k < 49; ++k) m = fmaxf(m, S[tid][k]);
        float sum = 0.f;
        for (int k = 0; k < 49; ++k) {
            float p = expf(S[tid][k] - m);
            S[tid][k] = p;
            sum += p;
        }
        float inv = 1.f / sum;
        for (int k = 0; k < 49; ++k) S[tid][k] *= inv;
    }
    __syncthreads();

    for (int i = tid; i < 49 * 32; i += 256) {
        int q = i >> 5, e = i & 31;
        float acc = 0.f;
        for (int k = 0; k < 49; ++k) acc += S[q][k] * Vs[k][e];
        int rp = bh * 7 + q / 7, cp = bw * 7 + q % 7;
        int fr = (rp + 3) % IMG, fc = (cp + 3) % IMG;
        att[((size_t)(b * IMG + fr) * IMG + fc) * DIM + n * 32 + e] = f2b(acc);
    }
}

// ---------------------------------------------------------------------------
extern "C" void kernel_launch(void* const* d_in, const int* in_sizes, int n_in,
                              void* d_out, int out_size, void* d_ws, size_t ws_size,
                              hipStream_t stream) {
    const float* x     = (const float*)d_in[0];
    const float* w_qkv = (const float*)d_in[1];
    const float* b_qkv = (const float*)d_in[2];
    const float* w_out = (const float*)d_in[3];
    const float* b_out = (const float*)d_in[4];
    float* out = (float*)d_out;

    char* wsp = (char*)d_ws;
    float* emb   = (float*)wsp;                                  // 16 KB slot
    u16*   wqkvt = (u16*)(wsp + 16384);                          // [1152][384]
    u16*   woutt = (u16*)(wsp + 16384 + 884736);                 // [384][384]
    const size_t fixed = 16384 + 884736 + 294912;                // 1,196,032 B

    // per-batch chunk cost (bytes): xb + qkv + att, all bf16
    const size_t perb = (size_t)ROWS_PER_B * (DIM + NQKV + DIM) * 2; // 12,042,240
    int nb = 16;
    while (nb > 2 && fixed + (size_t)nb * perb > ws_size) nb >>= 1;  // nb even (M%128)

    u16* xb   = (u16*)(wsp + fixed);
    u16* qkvb = xb   + (size_t)nb * ROWS_PER_B * DIM;
    u16* attb = qkvb + (size_t)nb * ROWS_PER_B * NQKV;

    emb_init_kernel<<<10, 256, 0, stream>>>(emb);
    cvt_transpose_bf16<<<(384 * 1152 + 255) / 256, 256, 0, stream>>>(w_qkv, wqkvt, 384, 1152);
    cvt_transpose_bf16<<<(384 * 384 + 255) / 256, 256, 0, stream>>>(w_out, woutt, 384, 384);

    for (int b0 = 0; b0 < 16; b0 += nb) {
        const int rows = nb * ROWS_PER_B;
        const float* xa = x + (size_t)b0 * ROWS_PER_B * DIM;

        cvt_f32_bf16<<<(rows * DIM / 4 + 255) / 256, 256, 0, stream>>>(
            xa, xb, rows * DIM / 4);

        mfma_gemm<0><<<dim3(NQKV / 128, rows / 128), 256, 0, stream>>>(
            xb, wqkvt, b_qkv, qkvb, nullptr, NQKV, DIM);

        attn_kernel<<<nb * 768, 256, 0, stream>>>(qkvb, emb, attb);

        mfma_gemm<1><<<dim3(DIM / 128, rows / 128), 256, 0, stream>>>(
            attb, woutt, b_out, nullptr, out + (size_t)b0 * ROWS_PER_B * DIM, DIM, DIM);
    }
}